// Round 12
// baseline (217.299 us; speedup 1.0000x reference)
//
#include <hip/hip_runtime.h>
#include <hip/hip_fp16.h>
#include <math.h>

#define NIMG 8
#define PNUM 4000
#define CNUM 91
#define DETK 100
#define LCAP 128
#define TOTALQ (NIMG * PNUM)
#define NEGV  -1000000000.0
#define NEGH  -500000000.0
#define CLAMP64 4.1351665567423558   // float64 nearest to log(1000/16)

// ---- workspace layout (bytes) ----
#define W_ACT 0                      // f64 [32000] score / NEGV
#define W_BH4 256000                 // float4 [32000] clipped box (f32 casts)
#define W_LAB 768000                 // u16 [32000]
#define W_B64 832000                 // f64 [32000][4] exact clipped boxes
#define WS_NEED 1856000

#if defined(__has_builtin)
# if __has_builtin(__builtin_amdgcn_readlane)
#  define RDLANE(v,l) __builtin_amdgcn_readlane((int)(v),(l))
# endif
#endif
#ifndef RDLANE
# define RDLANE(v,l) __shfl((int)(v),(l))
#endif

__device__ __forceinline__ unsigned long long rdlane64(unsigned long long v, int l) {
    const unsigned int lo = (unsigned int)RDLANE((unsigned int)v, l);
    const unsigned int hi = (unsigned int)RDLANE((unsigned int)(v >> 32), l);
    return ((unsigned long long)hi << 32) | lo;
}

// =====================================================================
// K1: fused softmax+decode. 128-thread blocks; 8 wave-passes of the
// validated 8-props/wave softmax (r11) -> LDS; barrier; 128 full-util
// decodes (validated expression sequence, r9-r11). No atomics.
// =====================================================================
extern "C" __global__ __launch_bounds__(128)
void k_sm_decode(const float* __restrict__ logits,
                 const float* __restrict__ deltas,
                 const float* __restrict__ props,
                 double* __restrict__ w_act,
                 float4* __restrict__ w_bh4,
                 unsigned short* __restrict__ w_lab,
                 double* __restrict__ w_b64)
{
    __shared__ double sS[128];
    __shared__ unsigned short sL[128];

    const int tid  = threadIdx.x;
    const int wv   = tid >> 6, lane = tid & 63;
    const int g    = lane >> 3, hl = lane & 7;
    const int blockbase = blockIdx.x * 128;

    for (int pass = 0; pass < 8; ++pass) {
        const int  local = wv * 64 + pass * 8 + g;
        const long wid   = blockbase + local;
        const float* lg  = logits + wid * CNUM;

        // lane owns classes c = hl + 8k (k=0..10), plus 88+hl for hl<3
        float lv[12];
        #pragma unroll
        for (int k = 0; k < 11; ++k) lv[k] = lg[hl + 8 * k];
        const bool hasLast = hl < 3;
        lv[11] = hasLast ? lg[88 + hl] : 0.0f;

        float mx = lv[0];
        #pragma unroll
        for (int k = 1; k < 11; ++k) mx = fmaxf(mx, lv[k]);
        if (hasLast) mx = fmaxf(mx, lv[11]);

        // fg argmax (classes >= 1), first-occurrence ties (ascending scan + strict >)
        float bv = -INFINITY; int bc = 0x7fffffff;
        #pragma unroll
        for (int k = 0; k < 11; ++k) {
            const int c = hl + 8 * k;
            if (c >= 1 && lv[k] > bv) { bv = lv[k]; bc = c; }
        }
        if (hasLast && lv[11] > bv) { bv = lv[11]; bc = 88 + hl; }

        #pragma unroll
        for (int s = 4; s; s >>= 1) {
            mx = fmaxf(mx, __shfl_xor(mx, s));
            const float ov = __shfl_xor(bv, s);
            const int   oc = __shfl_xor(bc, s);
            if (ov > bv || (ov == bv && oc < bc)) { bv = ov; bc = oc; }
        }

        double sum = 0.0;
        #pragma unroll
        for (int k = 0; k < 11; ++k) sum += exp((double)lv[k] - (double)mx);
        if (hasLast) sum += exp((double)lv[11] - (double)mx);
        #pragma unroll
        for (int s = 4; s; s >>= 1) sum += __shfl_xor(sum, s);

        if (hl == 0) {
            sS[local] = exp((double)bv - (double)mx) / sum;
            sL[local] = (unsigned short)bc;
        }
    }
    __syncthreads();

    // ---- decode phase: one thread per proposal, full lane utilization ----
    const long wid   = blockbase + tid;
    const double score = sS[tid];
    const int    label = (int)sL[tid];

    const float4 pr = *reinterpret_cast<const float4*>(props + wid * 4);
    const double x1p = (double)pr.x, y1p = (double)pr.y;
    const double x2p = (double)pr.z, y2p = (double)pr.w;
    const double w  = x2p - x1p, h = y2p - y1p;
    const double cx = x1p + 0.5 * w, cy = y1p + 0.5 * h;

    const float4 dl = *reinterpret_cast<const float4*>(
        deltas + wid * (CNUM * 4) + label * 4);
    const double dx = (double)dl.x / 10.0;
    const double dy = (double)dl.y / 10.0;
    const double dw = fmin((double)dl.z / 5.0, CLAMP64);
    const double dh = fmin((double)dl.w / 5.0, CLAMP64);

    const double pcx = dx * w + cx;
    const double pcy = dy * h + cy;
    const double pw  = exp(dw) * w;
    const double ph  = exp(dh) * h;

    double x1 = pcx - 0.5 * pw, y1 = pcy - 0.5 * ph;
    double x2 = pcx + 0.5 * pw, y2 = pcy + 0.5 * ph;
    x1 = fmin(fmax(x1, 0.0), 800.0);
    y1 = fmin(fmax(y1, 0.0), 800.0);
    x2 = fmin(fmax(x2, 0.0), 800.0);
    y2 = fmin(fmax(y2, 0.0), 800.0);

    const bool valid = ((x2 - x1) >= 0.01) && ((y2 - y1) >= 0.01) && (score > 0.05);

    w_act[wid] = valid ? score : NEGV;
    w_lab[wid] = (unsigned short)label;
    if (valid) {
        w_bh4[wid] = make_float4((float)x1, (float)y1, (float)x2, (float)y2);
        double* bx = w_b64 + wid * 4;
        bx[0] = x1; bx[1] = y1; bx[2] = x2; bx[3] = y2;
    }
}

// =====================================================================
// K2: fused NMS + topk. One block (1024 thr, 16 waves) per image.
// LDS-resident act; per-label lists via LDS atomics + wave-0 shfl
// prefix; per-wave register-row NMS (validated r9-r11, rank now via
// readlane over register keys); suppression marks in LDS; then the
// validated histogram topk on LDS act.  LDS ~138 KB (k_fused precedent).
// =====================================================================
#define NBINS 2304
#define CHW   36
#define NCHK  64

extern "C" __global__ __launch_bounds__(1024)
void k_nms_topk(const double* __restrict__ w_act,
                const float4* __restrict__ w_bh4,
                const unsigned short* __restrict__ w_lab,
                const double* __restrict__ w_b64,
                float* __restrict__ out)
{
    __shared__ double actL[PNUM];                 // 32000 B
    __shared__ unsigned short labL[PNUM];         // 8000
    __shared__ unsigned short list[PNUM];         // 8000
    __shared__ int cnt[96], off[96], cur[96];     // 1152
    __shared__ double wx1[16][LCAP], wy1[16][LCAP],
                      wx2[16][LCAP], wy2[16][LCAP];  // 65536
    __shared__ unsigned short wjj[16][LCAP];      // 4096
    __shared__ int hist[NBINS];                   // 9216
    __shared__ unsigned long long cKey[1024];     // 8192
    __shared__ int cIdx[1024];                    // 4096
    __shared__ unsigned long long rKey[DETK];     // 800
    __shared__ int rIdx[DETK];                    // 400
    __shared__ int sT, scnt;

    const int n   = blockIdx.x;
    const int tid = threadIdx.x;
    const long base = (long)n * PNUM;
    const unsigned long long KBASE = 0x3FA999999999999Aull >> 43;

    for (int j = tid; j < PNUM; j += 1024) {
        actL[j] = w_act[base + j];
        labL[j] = w_lab[base + j];
    }
    if (tid < 96) { cnt[tid] = 0; cur[tid] = 0; }
    for (int i = tid; i < NBINS; i += 1024) hist[i] = 0;
    if (tid < DETK) rIdx[tid] = -1;
    if (tid == 0) { sT = 0; scnt = 0; }
    __syncthreads();

    // ---- per-label counts of valid candidates ----
    for (int j = tid; j < PNUM; j += 1024)
        if (actL[j] > 0.0) atomicAdd(&cnt[labL[j]], 1);
    __syncthreads();

    // ---- exclusive prefix over labels 1..90, wave 0 only (no barriers) ----
    if (tid < 64) {
        const int l1 = tid + 1;                 // labels 1..64
        const int v = cnt[l1];
        int p = v;
        #pragma unroll
        for (int d = 1; d < 64; d <<= 1) {
            const int o = __shfl_up(p, d);
            if (tid >= d) p += o;
        }
        off[l1] = p - v;
        const int tot1 = __shfl(p, 63);
        const int l2 = 65 + tid;                // labels 65..90 on lanes 0..25
        const int v2 = (l2 < CNUM) ? cnt[l2] : 0;
        int p2 = v2;
        #pragma unroll
        for (int d = 1; d < 64; d <<= 1) {
            const int o = __shfl_up(p2, d);
            if (tid >= d) p2 += o;
        }
        if (l2 < CNUM) off[l2] = tot1 + p2 - v2;
    }
    __syncthreads();

    // ---- fill lists (order arbitrary; rank is order-invariant) ----
    for (int j = tid; j < PNUM; j += 1024)
        if (actL[j] > 0.0) {
            const int l = labL[j];
            const int p = atomicAdd(&cur[l], 1);
            list[off[l] + p] = (unsigned short)j;
        }
    __syncthreads();

    // ---- per-wave per-label NMS ----
    const int w = tid >> 6, lane = tid & 63;
    for (int l = 1 + w; l < CNUM; l += 16) {
        const int m = min(cnt[l], LCAP);
        if (m < 2) continue;
        const int sbase = off[l];
        const int s2 = lane + 64;
        const bool h1v = lane < m, h2v = s2 < m;

        int j1 = 0, j2 = 0;
        unsigned long long k1 = 0, k2 = 0;
        double a1x1=0,a1y1=0,a1x2=0,a1y2=0;
        double a2x1=0,a2y1=0,a2x2=0,a2y2=0;
        if (h1v) {
            j1 = list[sbase + lane];
            k1 = (unsigned long long)__double_as_longlong(actL[j1]);
            const double* bp = w_b64 + (base + j1) * 4;
            a1x1 = bp[0]; a1y1 = bp[1]; a1x2 = bp[2]; a1y2 = bp[3];
        }
        if (h2v) {
            j2 = list[sbase + s2];
            k2 = (unsigned long long)__double_as_longlong(actL[j2]);
            const double* bp = w_b64 + (base + j2) * 4;
            a2x1 = bp[0]; a2y1 = bp[1]; a2x2 = bp[2]; a2y2 = bp[3];
        }

        // rank by (key desc, j asc) via readlane over register keys
        int r1 = 0, r2 = 0;
        for (int q = 0; q < m; ++q) {
            unsigned long long kq; int jq;
            if (q < 64) { kq = rdlane64(k1, q); jq = RDLANE(j1, q); }
            else        { kq = rdlane64(k2, q - 64); jq = RDLANE(j2, q - 64); }
            r1 += (int)(h1v && ((kq > k1) || (kq == k1 && jq < j1)));
            r2 += (int)(h2v && ((kq > k2) || (kq == k2 && jq < j2)));
        }
        if (h1v) { wx1[w][r1]=a1x1; wy1[w][r1]=a1y1; wx2[w][r1]=a1x2; wy2[w][r1]=a1y2;
                   wjj[w][r1] = (unsigned short)j1; }
        if (h2v) { wx1[w][r2]=a2x1; wy1[w][r2]=a2y1; wx2[w][r2]=a2x2; wy2[w][r2]=a2y2;
                   wjj[w][r2] = (unsigned short)j2; }
        asm volatile("s_waitcnt lgkmcnt(0)" ::: "memory");   // same-wave DS in order

        // IoU bit-rows in registers (sorted positions lane, lane+64)
        double p1x1=0,p1y1=0,p1x2=0,p1y2=0,ar1=0;
        double p2x1=0,p2y1=0,p2x2=0,p2y2=0,ar2=0;
        if (h1v) { p1x1=wx1[w][lane]; p1y1=wy1[w][lane]; p1x2=wx2[w][lane]; p1y2=wy2[w][lane];
                   ar1 = (p1x2-p1x1)*(p1y2-p1y1); }
        if (h2v) { p2x1=wx1[w][s2]; p2y1=wy1[w][s2]; p2x2=wx2[w][s2]; p2y2=wy2[w][s2];
                   ar2 = (p2x2-p2x1)*(p2y2-p2y1); }
        unsigned long long rA0=0, rA1=0, rB0=0, rB1=0;
        for (int q = 0; q < m; ++q) {
            const double qx1 = wx1[w][q], qy1 = wy1[w][q];
            const double qx2 = wx2[w][q], qy2 = wy2[w][q];
            const double a2  = (qx2 - qx1) * (qy2 - qy1);
            if (h1v && q != lane) {
                const double ix = fmin(p1x2, qx2) - fmax(p1x1, qx1);
                const double iy = fmin(p1y2, qy2) - fmax(p1y1, qy1);
                const double inter = fmax(ix, 0.0) * fmax(iy, 0.0);
                const double uni = fmax(ar1 + a2 - inter, 1e-9);
                if (inter / uni > 0.5) { if (q < 64) rA0 |= 1ull << q; else rA1 |= 1ull << (q - 64); }
            }
            if (h2v && q != s2) {
                const double ix = fmin(p2x2, qx2) - fmax(p2x1, qx1);
                const double iy = fmin(p2y2, qy2) - fmax(p2y1, qy1);
                const double inter = fmax(ix, 0.0) * fmax(iy, 0.0);
                const double uni = fmax(ar2 + a2 - inter, 1e-9);
                if (inter / uni > 0.5) { if (q < 64) rB0 |= 1ull << q; else rB1 |= 1ull << (q - 64); }
            }
        }

        // serial greedy resolve (validated readlane chain)
        unsigned long long sa = 0, sb = 0;
        for (int i = 0; i < m; ++i) {
            unsigned long long w0, w1;
            bool kept;
            if (i < 64) {
                w0 = rdlane64(rA0, i); w1 = rdlane64(rA1, i);
                kept = !((sa >> i) & 1ull);
            } else {
                w0 = rdlane64(rB0, i - 64); w1 = rdlane64(rB1, i - 64);
                kept = !((sb >> (i - 64)) & 1ull);
            }
            if (kept) { sa |= w0; sb |= w1; }
        }

        if (h1v && ((sa >> lane) & 1ull)) actL[wjj[w][lane]] = NEGV;
        if (h2v && ((sb >> lane) & 1ull)) actL[wjj[w][s2]]   = NEGV;
    }
    __syncthreads();

    // ---- topk on LDS act (validated r11 scheme) ----
    for (int j = tid; j < PNUM; j += 1024) {
        const double a = actL[j];
        if (a > 0.0) {
            const unsigned long long k = (unsigned long long)__double_as_longlong(a);
            int b = (int)((k >> 43) - KBASE);
            b = min(max(b, 0), NBINS - 1);
            atomicAdd(&hist[b], 1);
        }
    }
    __syncthreads();

    if (tid < NCHK) {
        int s = 0;
        for (int b = 0; b < CHW; ++b) s += hist[tid * CHW + b];
        int suf = s;
        #pragma unroll
        for (int o2 = 1; o2 < NCHK; o2 <<= 1) {
            const int o = __shfl_down(suf, o2);
            suf += (tid + o2 < NCHK) ? o : 0;
        }
        const unsigned long long mk = __ballot(suf >= DETK);
        if (mk != 0ull) {
            const int ch  = 63 - __clzll(mk);
            const int Shi = (ch < NCHK - 1) ? __shfl(suf, ch + 1) : 0;
            int W = 0;
            if (tid < CHW) for (int b = tid; b < CHW; ++b) W += hist[ch * CHW + b];
            const unsigned long long mk2 = __ballot((tid < CHW) && (W + Shi >= DETK));
            if (tid == 0) sT = ch * CHW + (63 - __clzll(mk2));
        }
    }
    __syncthreads();
    const int T = sT;

    for (int j = tid; j < PNUM; j += 1024) {
        const double a = actL[j];
        if (a > 0.0) {
            const unsigned long long k = (unsigned long long)__double_as_longlong(a);
            int b = (int)((k >> 43) - KBASE);
            b = min(max(b, 0), NBINS - 1);
            if (b >= T) {
                const int p = atomicAdd(&scnt, 1);
                if (p < 1024) { cKey[p] = k; cIdx[p] = j; }
            }
        }
    }
    __syncthreads();
    const int cnt2 = min(scnt, 1024);

    for (int s = tid; s < cnt2; s += 1024) {
        const unsigned long long ks = cKey[s];
        const int is = cIdx[s];
        int rank = 0;
        for (int q = 0; q < cnt2; ++q) {
            const unsigned long long kq = cKey[q];
            rank += (int)((kq > ks) || (kq == ks && cIdx[q] < is));
        }
        if (rank < DETK) { rKey[rank] = ks; rIdx[rank] = is; }
    }
    __syncthreads();

    if (tid < DETK) {
        const int o = n * DETK + tid;
        const int idx = rIdx[tid];
        const bool kp = (idx >= 0);
        float lab = 0.f, sc = 0.f, b0 = 0.f, b1 = 0.f, b2 = 0.f, b3 = 0.f;
        if (kp) {
            lab = (float)labL[idx];
            sc  = (float)__longlong_as_double((long long)rKey[tid]);
            const float4 bh = w_bh4[base + idx];
            b0 = bh.x; b1 = bh.y; b2 = bh.z; b3 = bh.w;
        }
        out[o]               = lab;
        out[NIMG * DETK + o] = sc;
        out[2 * NIMG * DETK + o * 4 + 0] = b0;
        out[2 * NIMG * DETK + o * 4 + 1] = b1;
        out[2 * NIMG * DETK + o * 4 + 2] = b2;
        out[2 * NIMG * DETK + o * 4 + 3] = b3;
    }
}

// =====================================================================
// Fallback (proven round-3 fused kernel) for tiny ws_size.
// =====================================================================
extern "C" __global__ __launch_bounds__(1024)
void k_fused(const float* __restrict__ logits,
             const float* __restrict__ deltas,
             const float* __restrict__ props,
             float* __restrict__ out)
{
    __shared__ float   bh0[PNUM], bh1[PNUM], bh2[PNUM], bh3[PNUM];
    __shared__ __half  bl0[PNUM], bl1[PNUM], bl2[PNUM], bl3[PNUM];
    __shared__ double  act[PNUM];
    __shared__ unsigned short slab[PNUM];
    __shared__ double  redV[16];
    __shared__ int     redI[16];
    __shared__ double  pbox[4];
    __shared__ int     pidx, pkeep, plab;
    __shared__ int     kidx[DETK], kkeep[DETK];
    __shared__ double  kscore[DETK];
    __shared__ double  kbox[DETK][4];

    const int n   = blockIdx.x;
    const int tid = threadIdx.x;

    for (int j = tid; j < PNUM; j += 1024) {
        const long q = (long)n * PNUM + j;
        const float* lg = logits + q * CNUM;
        float ml = lg[0];
        float bv = lg[1];
        int   lab = 1;
        for (int c = 1; c < CNUM; ++c) {
            const float v = lg[c];
            ml = fmaxf(ml, v);
            if (c >= 2 && v > bv) { bv = v; lab = c; }
        }
        const double m = (double)ml;
        double sum = 0.0;
        for (int c = 0; c < CNUM; ++c) sum += exp((double)lg[c] - m);
        const double score = exp((double)bv - m) / sum;

        const float* pr = props + q * 4;
        const double x1p = (double)pr[0], y1p = (double)pr[1];
        const double x2p = (double)pr[2], y2p = (double)pr[3];
        const double w  = x2p - x1p, h = y2p - y1p;
        const double cx = x1p + 0.5 * w, cy = y1p + 0.5 * h;
        const float* dl = deltas + q * (CNUM * 4) + lab * 4;
        const double dx = (double)dl[0] / 10.0;
        const double dy = (double)dl[1] / 10.0;
        const double dw = fmin((double)dl[2] / 5.0, CLAMP64);
        const double dh = fmin((double)dl[3] / 5.0, CLAMP64);
        const double pcx = dx * w + cx;
        const double pcy = dy * h + cy;
        const double pw  = exp(dw) * w;
        const double ph  = exp(dh) * h;
        double x1 = pcx - 0.5 * pw, y1 = pcy - 0.5 * ph;
        double x2 = pcx + 0.5 * pw, y2 = pcy + 0.5 * ph;
        x1 = fmin(fmax(x1, 0.0), 800.0);
        y1 = fmin(fmax(y1, 0.0), 800.0);
        x2 = fmin(fmax(x2, 0.0), 800.0);
        y2 = fmin(fmax(y2, 0.0), 800.0);
        const bool valid = ((x2 - x1) >= 0.01) && ((y2 - y1) >= 0.01) && (score > 0.05);
        act[j]  = valid ? score : NEGV;
        slab[j] = (unsigned short)lab;
        const float h0 = (float)x1, h1 = (float)y1, h2 = (float)x2, h3 = (float)y2;
        bh0[j] = h0; bh1[j] = h1; bh2[j] = h2; bh3[j] = h3;
        bl0[j] = __float2half((float)(x1 - (double)h0));
        bl1[j] = __float2half((float)(y1 - (double)h1));
        bl2[j] = __float2half((float)(x2 - (double)h2));
        bl3[j] = __float2half((float)(y2 - (double)h3));
    }
    __syncthreads();

    for (int k = 0; k < DETK; ++k) {
        double bv = -INFINITY;
        int    bi = 0x7fffffff;
        #pragma unroll
        for (int t = 0; t < 4; ++t) {
            const int j = tid + t * 1024;
            if (j < PNUM) {
                const double v = act[j];
                if (v > bv) { bv = v; bi = j; }
            }
        }
        #pragma unroll
        for (int s = 32; s; s >>= 1) {
            const double ov = __shfl_xor(bv, s);
            const int    oi = __shfl_xor(bi, s);
            if (ov > bv || (ov == bv && oi < bi)) { bv = ov; bi = oi; }
        }
        if ((tid & 63) == 0) { redV[tid >> 6] = bv; redI[tid >> 6] = bi; }
        __syncthreads();
        if (tid < 64) {
            bv = (tid < 16) ? redV[tid] : -INFINITY;
            bi = (tid < 16) ? redI[tid] : 0x7fffffff;
            #pragma unroll
            for (int s = 8; s; s >>= 1) {
                const double ov = __shfl_xor(bv, s);
                const int    oi = __shfl_xor(bi, s);
                if (ov > bv || (ov == bv && oi < bi)) { bv = ov; bi = oi; }
            }
            if (tid == 0) {
                const int kp = (bv > NEGH) ? 1 : 0;
                pidx = bi; pkeep = kp; plab = (int)slab[bi];
                kidx[k] = bi; kkeep[k] = kp; kscore[k] = bv;
                const double b0 = (double)bh0[bi] + (double)__half2float(bl0[bi]);
                const double b1 = (double)bh1[bi] + (double)__half2float(bl1[bi]);
                const double b2 = (double)bh2[bi] + (double)__half2float(bl2[bi]);
                const double b3 = (double)bh3[bi] + (double)__half2float(bl3[bi]);
                pbox[0] = b0; pbox[1] = b1; pbox[2] = b2; pbox[3] = b3;
                kbox[k][0] = b0; kbox[k][1] = b1; kbox[k][2] = b2; kbox[k][3] = b3;
            }
        }
        __syncthreads();

        const int    pick = pidx;
        const int    kp   = pkeep;
        const int    pl   = plab;
        const double px1 = pbox[0], py1 = pbox[1], px2 = pbox[2], py2 = pbox[3];
        const double a1  = (px2 - px1) * (py2 - py1);
        #pragma unroll
        for (int t = 0; t < 4; ++t) {
            const int j = tid + t * 1024;
            if (j >= PNUM) break;
            if (j == pick) { act[j] = NEGV; continue; }
            if (!kp) continue;
            if ((int)slab[j] != pl) continue;
            if (act[j] <= NEGH) continue;
            const double qx1 = (double)bh0[j] + (double)__half2float(bl0[j]);
            const double qy1 = (double)bh1[j] + (double)__half2float(bl1[j]);
            const double qx2 = (double)bh2[j] + (double)__half2float(bl2[j]);
            const double qy2 = (double)bh3[j] + (double)__half2float(bl3[j]);
            const double ix = fmin(px2, qx2) - fmax(px1, qx1);
            const double iy = fmin(py2, qy2) - fmax(py1, qy1);
            const double inter = fmax(ix, 0.0) * fmax(iy, 0.0);
            const double a2  = (qx2 - qx1) * (qy2 - qy1);
            const double uni = fmax(a1 + a2 - inter, 1e-9);
            if (inter / uni > 0.5) act[j] = NEGV;
        }
        __syncthreads();
    }

    if (tid < DETK) {
        const int kp = kkeep[tid];
        const int o  = n * DETK + tid;
        out[o]               = kp ? (float)slab[kidx[tid]] : 0.0f;
        out[NIMG * DETK + o] = kp ? (float)kscore[tid] : 0.0f;
        #pragma unroll
        for (int i = 0; i < 4; ++i)
            out[2 * NIMG * DETK + o * 4 + i] = kp ? (float)kbox[tid][i] : 0.0f;
    }
}

extern "C" void kernel_launch(void* const* d_in, const int* in_sizes, int n_in,
                              void* d_out, int out_size, void* d_ws, size_t ws_size,
                              hipStream_t stream)
{
    const float* logits = (const float*)d_in[1];
    const float* deltas = (const float*)d_in[2];
    const float* props  = (const float*)d_in[3];
    float* out = (float*)d_out;
    char* ws = (char*)d_ws;

    if (ws_size >= (size_t)WS_NEED) {
        double*         w_act = (double*)(ws + W_ACT);
        float4*         w_bh4 = (float4*)(ws + W_BH4);
        unsigned short* w_lab = (unsigned short*)(ws + W_LAB);
        double*         w_b64 = (double*)(ws + W_B64);

        hipLaunchKernelGGL(k_sm_decode, dim3(TOTALQ / 128), dim3(128), 0, stream,
                           logits, deltas, props, w_act, w_bh4, w_lab, w_b64);
        hipLaunchKernelGGL(k_nms_topk, dim3(NIMG), dim3(1024), 0, stream,
                           w_act, w_bh4, w_lab, w_b64, out);
    } else {
        hipLaunchKernelGGL(k_fused, dim3(NIMG), dim3(1024), 0, stream,
                           logits, deltas, props, out);
    }
}